// Round 1
// 2433.878 us; speedup vs baseline: 1.2395x; 1.2395x over previous
//
#include <hip/hip_runtime.h>

constexpr int N_NODES = 50000;
constexpr int N_EDGES = 1600000;
// DIM_H = 128, N_HEADS = 8, OUT_DIM = 16

// ---------------------------------------------------------------------------
// Stage W (128x128, k-major) into LDS as W^T with XOR-swizzled 16B chunks:
// element W[k][d] lives at WT[d*128 + ((k>>2)^(d&31))*4 + (k&3)].
// CONFLICT-FREE staging: each lane gathers W[4kc..4kc+3][d] (4 coalesced
// global loads across the wave) and issues ONE ds_write_b128. Across a wave
// d is lane-contiguous with kc fixed, so each 16-lane phase covers each
// (d&31)&7 residue exactly twice -> 2 lanes/bank-group = free.
// (Old version did 64 scalar writes/thread with d=4*lane+j -> 2 banks for
//  32 lanes = 16-way conflict; that was ~28% of edge_kernel cycles.)
// ---------------------------------------------------------------------------
__device__ __forceinline__ void stage_W_swizzled(const float* __restrict__ W,
                                                 float* WT, int tid) {
#pragma unroll
    for (int it = 0; it < 16; ++it) {
        int idx = tid + 256 * it;   // 0..4095 enumerates (d, kc)
        int d  = idx & 127;
        int kc = idx >> 7;          // wave-uniform (64-blocks don't cross kc)
        float4 w;
        w.x = W[(4 * kc + 0) * 128 + d];
        w.y = W[(4 * kc + 1) * 128 + d];
        w.z = W[(4 * kc + 2) * 128 + d];
        w.w = W[(4 * kc + 3) * 128 + d];
        *(float4*)&WT[d * 128 + ((kc ^ (d & 31)) << 2)] = w;
    }
}

__device__ __forceinline__ float4 read_WT(const float* WT, int d, int kc) {
    return *(const float4*)&WT[d * 128 + ((kc ^ (d & 31)) << 2)];
}

// ---------------------------------------------------------------------------
// Node projection: OUT[M x 128] = A[M x 128] @ W[128 x 128], fp32.
// PERSISTENT: 512 blocks (2/CU), W staged ONCE per block, grid-stride over
// 32-row tiles. Block = 256 thr (4 waves), wave owns 8 rows, lane owns output
// dims (lane, lane+64). LDS = 64KB WT + 16KB As = 80KB -> 2 blocks/CU.
// ---------------------------------------------------------------------------
__global__ __launch_bounds__(256) void proj_kernel(const float* __restrict__ A,
                                                   const float* __restrict__ W,
                                                   float* __restrict__ OUT, int M,
                                                   int n_tiles) {
    __shared__ float WT[128 * 128];
    __shared__ float As[32 * 128];
    int tid = threadIdx.x;
    stage_W_swizzled(W, WT, tid);           // first __syncthreads covers this
    int wave = tid >> 6, lane = tid & 63;
    const float4 zero4 = {0.f, 0.f, 0.f, 0.f};
    for (int t = blockIdx.x; t < n_tiles; t += gridDim.x) {
        int base = t * 32;
#pragma unroll
        for (int i = 0; i < 4; ++i) {
            int f = tid + 256 * i;          // float4 index 0..1023
            int row = f >> 5, c4 = f & 31;
            float4 v = (base + row < M)
                           ? ((const float4*)A)[(size_t)(base + row) * 32 + c4]
                           : zero4;
            *(float4*)&As[row * 128 + (c4 << 2)] = v;
        }
        __syncthreads();
        float acc0[8] = {}, acc1[8] = {};
        for (int kc = 0; kc < 32; ++kc) {
            float4 w0 = read_WT(WT, lane, kc);
            float4 w1 = read_WT(WT, lane + 64, kc);
#pragma unroll
            for (int r = 0; r < 8; ++r) {
                float4 a = *(float4*)&As[(wave * 8 + r) * 128 + (kc << 2)];
                acc0[r] += a.x * w0.x + a.y * w0.y + a.z * w0.z + a.w * w0.w;
                acc1[r] += a.x * w1.x + a.y * w1.y + a.z * w1.z + a.w * w1.w;
            }
        }
#pragma unroll
        for (int r = 0; r < 8; ++r) {
            int row = base + wave * 8 + r;
            if (row < M) {
                OUT[(size_t)row * 128 + lane] = acc0[r];
                OUT[(size_t)row * 128 + lane + 64] = acc1[r];
            }
        }
        __syncthreads();                    // As reads done before next stage
    }
}

// ---------------------------------------------------------------------------
// Fused edge kernel (persistent): WE staged once per block; per 32-edge tile:
// stage edge_attr, prefetch eidx (wave-uniform -> SGPR) and K/Q/V gathers
// BEFORE the GEMM so their L2/L3 latency hides under the 2048 FMAs; then
// Eh in registers, score = exp(clip(sum K*Q*Eh * 0.25, -5, 5)) per head,
// atomic scatter onto wV[dst] / Z[dst].
// Lane l owns dims (l, l+64) -> heads (l>>4, (l>>4)+4); per-head reduction is
// shfl_xor over the 16-lane group.
// ---------------------------------------------------------------------------
__global__ __launch_bounds__(256) void edge_kernel(const float* __restrict__ EA,
                                                   const float* __restrict__ WE,
                                                   const int* __restrict__ eidx,
                                                   const float* __restrict__ Qh,
                                                   const float* __restrict__ Kh,
                                                   const float* __restrict__ Vh,
                                                   float* __restrict__ wV,
                                                   float* __restrict__ Z,
                                                   int n_tiles) {
    __shared__ float WT[128 * 128];
    __shared__ float As[32 * 128];
    int tid = threadIdx.x;
    stage_W_swizzled(WE, WT, tid);
    int wave = tid >> 6, lane = tid & 63;
    int head0 = lane >> 4;
    const float inv_sqrt_d = 0.25f;         // 1/sqrt(16)
    for (int t = blockIdx.x; t < n_tiles; t += gridDim.x) {
        int base = t * 32;                  // 1.6M % 32 == 0, no guards
#pragma unroll
        for (int i = 0; i < 4; ++i) {
            int f = tid + 256 * i;
            int row = f >> 5, c4 = f & 31;
            *(float4*)&As[row * 128 + (c4 << 2)] =
                ((const float4*)EA)[(size_t)(base + row) * 32 + c4];
        }
        // wave-uniform edge indices (compiler scalarizes -> s_load)
        int srcs[8], dsts[8];
#pragma unroll
        for (int r = 0; r < 8; ++r) {
            int e = base + wave * 8 + r;
            srcs[r] = eidx[e];
            dsts[r] = eidx[N_EDGES + e];
        }
        __syncthreads();
        // issue all gathers now; uses are after the GEMM -> latency hidden
        float k0[8], k1[8], q0[8], q1[8], v0[8], v1[8];
#pragma unroll
        for (int r = 0; r < 8; ++r) {
            size_t so = (size_t)srcs[r] * 128, dofs = (size_t)dsts[r] * 128;
            k0[r] = Kh[so + lane];   k1[r] = Kh[so + lane + 64];
            q0[r] = Qh[dofs + lane]; q1[r] = Qh[dofs + lane + 64];
            v0[r] = Vh[so + lane];   v1[r] = Vh[so + lane + 64];
        }
        float e0[8] = {}, e1[8] = {};
        for (int kc = 0; kc < 32; ++kc) {
            float4 w0 = read_WT(WT, lane, kc);
            float4 w1 = read_WT(WT, lane + 64, kc);
#pragma unroll
            for (int r = 0; r < 8; ++r) {
                float4 a = *(float4*)&As[(wave * 8 + r) * 128 + (kc << 2)];
                e0[r] += a.x * w0.x + a.y * w0.y + a.z * w0.z + a.w * w0.w;
                e1[r] += a.x * w1.x + a.y * w1.y + a.z * w1.z + a.w * w1.w;
            }
        }
#pragma unroll
        for (int r = 0; r < 8; ++r) {
            float p0 = k0[r] * q0[r] * e0[r];
            float p1 = k1[r] * q1[r] * e1[r];
#pragma unroll
            for (int off = 1; off < 16; off <<= 1) {
                p0 += __shfl_xor(p0, off);
                p1 += __shfl_xor(p1, off);
            }
            float s0 = __expf(fminf(fmaxf(p0 * inv_sqrt_d, -5.f), 5.f));
            float s1 = __expf(fminf(fmaxf(p1 * inv_sqrt_d, -5.f), 5.f));
            size_t dofs = (size_t)dsts[r] * 128;
            atomicAdd(&wV[dofs + lane], v0[r] * s0);
            atomicAdd(&wV[dofs + lane + 64], v1[r] * s1);
            if ((lane & 15) == 0) {
                atomicAdd(&Z[dsts[r] * 8 + head0], s0);
                atomicAdd(&Z[dsts[r] * 8 + head0 + 4], s1);
            }
        }
        __syncthreads();                    // As reads done before next stage
    }
}

// ---------------------------------------------------------------------------
// h_out = wV / (Z + 1e-6)
// ---------------------------------------------------------------------------
__global__ __launch_bounds__(256) void norm_kernel(const float* __restrict__ wV,
                                                   const float* __restrict__ Z,
                                                   float* __restrict__ out) {
    int i = blockIdx.x * 256 + threadIdx.x;     // out_size = 6.4M, exact grid
    int n = i >> 7;
    int head = (i & 127) >> 4;
    out[i] = wV[i] / (Z[n * 8 + head] + 1e-6f);
}

extern "C" void kernel_launch(void* const* d_in, const int* in_sizes, int n_in,
                              void* d_out, int out_size, void* d_ws, size_t ws_size,
                              hipStream_t stream) {
    const float* h  = (const float*)d_in[0];
    const float* ea = (const float*)d_in[1];
    const float* WQ = (const float*)d_in[2];
    const float* WK = (const float*)d_in[3];
    const float* WV = (const float*)d_in[4];
    const float* WE = (const float*)d_in[5];
    const int*  eix = (const int*)d_in[6];

    float* ws = (float*)d_ws;
    float* Qh = ws;                  // 6.4M floats
    float* Kh = ws + 6400000;        // 6.4M
    float* Vh = ws + 12800000;       // 6.4M
    float* wV = ws + 19200000;       // 6.4M
    float* Z  = ws + 25600000;       // 400K
    // total 26.0M floats = 104 MB of ws

    // zero the accumulators (ws is poisoned 0xAA before every timed call)
    hipMemsetAsync(wV, 0, (size_t)(6400000 + 400000) * sizeof(float), stream);

    const int PERSIST_BLOCKS = 512;  // exactly 2 blocks/CU (80KB LDS each)
    int n_node_tiles = (N_NODES + 31) / 32;      // 1563
    proj_kernel<<<PERSIST_BLOCKS, 256, 0, stream>>>(h, WQ, Qh, N_NODES, n_node_tiles);
    proj_kernel<<<PERSIST_BLOCKS, 256, 0, stream>>>(h, WK, Kh, N_NODES, n_node_tiles);
    proj_kernel<<<PERSIST_BLOCKS, 256, 0, stream>>>(h, WV, Vh, N_NODES, n_node_tiles);

    edge_kernel<<<PERSIST_BLOCKS, 256, 0, stream>>>(ea, WE, eix, Qh, Kh, Vh, wV, Z,
                                                    N_EDGES / 32);

    norm_kernel<<<out_size / 256, 256, 0, stream>>>(wV, Z, (float*)d_out);
}

// Round 3
// 2124.454 us; speedup vs baseline: 1.4201x; 1.1456x over previous
//
#include <hip/hip_runtime.h>

constexpr int N_NODES = 50000;
constexpr int N_EDGES = 1600000;
// DIM_H = 128, N_HEADS = 8, OUT_DIM = 16

// ---------------------------------------------------------------------------
// Stage W (128x128, k-major) into LDS as W^T with XOR-swizzled 16B chunks:
// element W[k][d] lives at WT[d*128 + ((k>>2)^(d&31))*4 + (k&3)].
// Conflict-free: each lane gathers W[4kc..4kc+3][d] (4 coalesced global
// loads across the wave) and issues ONE ds_write_b128; d is lane-contiguous
// so each 16-lane phase covers each bank-group exactly twice (= free).
// ---------------------------------------------------------------------------
__device__ __forceinline__ void stage_W_swizzled(const float* __restrict__ W,
                                                 float* WT, int tid) {
#pragma unroll
    for (int it = 0; it < 16; ++it) {
        int idx = tid + 256 * it;   // 0..4095 enumerates (d, kc)
        int d  = idx & 127;
        int kc = idx >> 7;          // wave-uniform
        float4 w;
        w.x = W[(4 * kc + 0) * 128 + d];
        w.y = W[(4 * kc + 1) * 128 + d];
        w.z = W[(4 * kc + 2) * 128 + d];
        w.w = W[(4 * kc + 3) * 128 + d];
        *(float4*)&WT[d * 128 + ((kc ^ (d & 31)) << 2)] = w;
    }
}

__device__ __forceinline__ float4 read_WT(const float* WT, int d, int kc) {
    return *(const float4*)&WT[d * 128 + ((kc ^ (d & 31)) << 2)];
}

// ---------------------------------------------------------------------------
// Node projection: OUT[M x 128] = A[M x 128] @ W[128 x 128], fp32.
// PERSISTENT: 512 blocks (2/CU), W staged ONCE per block, grid-stride over
// 32-row tiles. BARRIER-FREE main loop: each wave stages ITS OWN 8 rows of
// As (nobody else reads them; DS ops are in-order per wave), so the only
// __syncthreads is the one after WT staging. No per-tile vmcnt(0) drain.
// LDS = 64KB WT + 16KB As = 80KB -> 2 blocks/CU.
// ---------------------------------------------------------------------------
__global__ __launch_bounds__(256) void proj_kernel(const float* __restrict__ A,
                                                   const float* __restrict__ W,
                                                   float* __restrict__ OUT, int M,
                                                   int n_tiles) {
    __shared__ float WT[128 * 128];
    __shared__ float As[32 * 128];
    int tid = threadIdx.x;
    stage_W_swizzled(W, WT, tid);
    __syncthreads();                        // WT visible to all waves
    int wave = tid >> 6, lane = tid & 63;
    const float4 zero4 = {0.f, 0.f, 0.f, 0.f};
    int c4 = lane & 31;
    for (int t = blockIdx.x; t < n_tiles; t += gridDim.x) {
        int base = t * 32;
        // wave-private staging of rows [wave*8, wave*8+8)
#pragma unroll
        for (int i = 0; i < 4; ++i) {
            int f = lane + 64 * i;          // 0..255
            int row = wave * 8 + (f >> 5);
            float4 v = (base + row < M)
                           ? ((const float4*)A)[(size_t)(base + row) * 32 + c4]
                           : zero4;
            *(float4*)&As[row * 128 + (c4 << 2)] = v;
        }
        float acc0[8] = {}, acc1[8] = {};
        for (int kc = 0; kc < 32; ++kc) {
            float4 w0 = read_WT(WT, lane, kc);
            float4 w1 = read_WT(WT, lane + 64, kc);
#pragma unroll
            for (int r = 0; r < 8; ++r) {
                float4 a = *(float4*)&As[(wave * 8 + r) * 128 + (kc << 2)];
                acc0[r] = fmaf(a.x, w0.x, acc0[r]);
                acc0[r] = fmaf(a.y, w0.y, acc0[r]);
                acc0[r] = fmaf(a.z, w0.z, acc0[r]);
                acc0[r] = fmaf(a.w, w0.w, acc0[r]);
                acc1[r] = fmaf(a.x, w1.x, acc1[r]);
                acc1[r] = fmaf(a.y, w1.y, acc1[r]);
                acc1[r] = fmaf(a.z, w1.z, acc1[r]);
                acc1[r] = fmaf(a.w, w1.w, acc1[r]);
            }
        }
#pragma unroll
        for (int r = 0; r < 8; ++r) {
            int row = base + wave * 8 + r;
            if (row < M) {
                OUT[(size_t)row * 128 + lane] = acc0[r];
                OUT[(size_t)row * 128 + lane + 64] = acc1[r];
            }
        }
        // no barrier: As rows are wave-private; DS pipe is in-order per wave
    }
}

// ---------------------------------------------------------------------------
// Fused edge kernel (persistent, barrier-free main loop): WE staged once per
// block; per 32-edge tile each wave stages its own 8 edge_attr rows, issues
// eidx + K/Q/V gathers early (latency hidden under the 2048-FMA GEMM), then
// Eh in registers, score = exp(clip(sum K*Q*Eh * 0.25, -5, 5)) per head,
// fire-and-forget atomic scatter onto wV[dst] / Z[dst]. With no per-tile
// __syncthreads there is no vmcnt(0) drain, so atomics from tile t overlap
// the GEMM of tile t+1.
// Lane l owns dims (l, l+64) -> heads (l>>4, (l>>4)+4); per-head reduction is
// shfl_xor over the 16-lane group.
// ---------------------------------------------------------------------------
__global__ __launch_bounds__(256) void edge_kernel(const float* __restrict__ EA,
                                                   const float* __restrict__ WE,
                                                   const int* __restrict__ eidx,
                                                   const float* __restrict__ Qh,
                                                   const float* __restrict__ Kh,
                                                   const float* __restrict__ Vh,
                                                   float* __restrict__ wV,
                                                   float* __restrict__ Z,
                                                   int n_tiles) {
    __shared__ float WT[128 * 128];
    __shared__ float As[32 * 128];
    int tid = threadIdx.x;
    stage_W_swizzled(WE, WT, tid);
    __syncthreads();                        // WT visible to all waves
    int wave = tid >> 6, lane = tid & 63;
    int head0 = lane >> 4;
    int c4 = lane & 31;
    const float inv_sqrt_d = 0.25f;         // 1/sqrt(16)
    for (int t = blockIdx.x; t < n_tiles; t += gridDim.x) {
        int base = t * 32;                  // 1.6M % 32 == 0, no guards
        // wave-private staging of edge_attr rows [wave*8, wave*8+8)
#pragma unroll
        for (int i = 0; i < 4; ++i) {
            int f = lane + 64 * i;
            int row = wave * 8 + (f >> 5);
            *(float4*)&As[row * 128 + (c4 << 2)] =
                ((const float4*)EA)[(size_t)(base + row) * 32 + c4];
        }
        // wave-uniform edge indices
        int srcs[8], dsts[8];
#pragma unroll
        for (int r = 0; r < 8; ++r) {
            int e = base + wave * 8 + r;
            srcs[r] = eidx[e];
            dsts[r] = eidx[N_EDGES + e];
        }
        // issue all gathers now; uses are after the GEMM -> latency hidden
        float k0[8], k1[8], q0[8], q1[8], v0[8], v1[8];
#pragma unroll
        for (int r = 0; r < 8; ++r) {
            size_t so = (size_t)srcs[r] * 128, dofs = (size_t)dsts[r] * 128;
            k0[r] = Kh[so + lane];   k1[r] = Kh[so + lane + 64];
            q0[r] = Qh[dofs + lane]; q1[r] = Qh[dofs + lane + 64];
            v0[r] = Vh[so + lane];   v1[r] = Vh[so + lane + 64];
        }
        float e0[8] = {}, e1[8] = {};
        for (int kc = 0; kc < 32; ++kc) {
            float4 w0 = read_WT(WT, lane, kc);
            float4 w1 = read_WT(WT, lane + 64, kc);
#pragma unroll
            for (int r = 0; r < 8; ++r) {
                float4 a = *(float4*)&As[(wave * 8 + r) * 128 + (kc << 2)];
                e0[r] = fmaf(a.x, w0.x, e0[r]);
                e0[r] = fmaf(a.y, w0.y, e0[r]);
                e0[r] = fmaf(a.z, w0.z, e0[r]);
                e0[r] = fmaf(a.w, w0.w, e0[r]);
                e1[r] = fmaf(a.x, w1.x, e1[r]);
                e1[r] = fmaf(a.y, w1.y, e1[r]);
                e1[r] = fmaf(a.z, w1.z, e1[r]);
                e1[r] = fmaf(a.w, w1.w, e1[r]);
            }
        }
#pragma unroll
        for (int r = 0; r < 8; ++r) {
            float p0 = k0[r] * q0[r] * e0[r];
            float p1 = k1[r] * q1[r] * e1[r];
#pragma unroll
            for (int off = 1; off < 16; off <<= 1) {
                p0 += __shfl_xor(p0, off);
                p1 += __shfl_xor(p1, off);
            }
            float s0 = __expf(fminf(fmaxf(p0 * inv_sqrt_d, -5.f), 5.f));
            float s1 = __expf(fminf(fmaxf(p1 * inv_sqrt_d, -5.f), 5.f));
            size_t dofs = (size_t)dsts[r] * 128;
            atomicAdd(&wV[dofs + lane], v0[r] * s0);
            atomicAdd(&wV[dofs + lane + 64], v1[r] * s1);
            if ((lane & 15) == 0) {
                atomicAdd(&Z[dsts[r] * 8 + head0], s0);
                atomicAdd(&Z[dsts[r] * 8 + head0 + 4], s1);
            }
        }
        // no barrier: atomics are fire-and-forget, As rows wave-private
    }
}

// ---------------------------------------------------------------------------
// h_out = wV / (Z + 1e-6)
// ---------------------------------------------------------------------------
__global__ __launch_bounds__(256) void norm_kernel(const float* __restrict__ wV,
                                                   const float* __restrict__ Z,
                                                   float* __restrict__ out) {
    int i = blockIdx.x * 256 + threadIdx.x;     // out_size = 6.4M, exact grid
    int n = i >> 7;
    int head = (i & 127) >> 4;
    out[i] = wV[i] / (Z[n * 8 + head] + 1e-6f);
}

extern "C" void kernel_launch(void* const* d_in, const int* in_sizes, int n_in,
                              void* d_out, int out_size, void* d_ws, size_t ws_size,
                              hipStream_t stream) {
    const float* h  = (const float*)d_in[0];
    const float* ea = (const float*)d_in[1];
    const float* WQ = (const float*)d_in[2];
    const float* WK = (const float*)d_in[3];
    const float* WV = (const float*)d_in[4];
    const float* WE = (const float*)d_in[5];
    const int*  eix = (const int*)d_in[6];

    float* ws = (float*)d_ws;
    float* Qh = ws;                  // 6.4M floats
    float* Kh = ws + 6400000;        // 6.4M
    float* Vh = ws + 12800000;       // 6.4M
    float* wV = ws + 19200000;       // 6.4M
    float* Z  = ws + 25600000;       // 400K
    // total 26.0M floats = 104 MB of ws

    // zero the accumulators (ws is poisoned 0xAA before every timed call)
    hipMemsetAsync(wV, 0, (size_t)(6400000 + 400000) * sizeof(float), stream);

    const int PERSIST_BLOCKS = 512;  // exactly 2 blocks/CU (80KB LDS each)
    int n_node_tiles = (N_NODES + 31) / 32;      // 1563
    proj_kernel<<<PERSIST_BLOCKS, 256, 0, stream>>>(h, WQ, Qh, N_NODES, n_node_tiles);
    proj_kernel<<<PERSIST_BLOCKS, 256, 0, stream>>>(h, WK, Kh, N_NODES, n_node_tiles);
    proj_kernel<<<PERSIST_BLOCKS, 256, 0, stream>>>(h, WV, Vh, N_NODES, n_node_tiles);

    edge_kernel<<<PERSIST_BLOCKS, 256, 0, stream>>>(ea, WE, eix, Qh, Kh, Vh, wV, Z,
                                                    N_EDGES / 32);

    norm_kernel<<<out_size / 256, 256, 0, stream>>>(wV, Z, (float*)d_out);
}